// Round 1
// baseline (409.491 us; speedup 1.0000x reference)
//
#include <hip/hip_runtime.h>

// BilinearInterpolation: B=16, H=W=512, C=16, OUT_H=OUT_W=512, fp32.
// theta = [[s,0,tx],[0,s,ty]] per batch. x = 0.5*(s*x_lin[j]+tx+1)*W,
// y = 0.5*(s*y_lin[i]+ty+1)*H, x_lin/y_lin = linspace(-1,1,512).
// x0 = trunc-toward-zero (numpy astype int32 == C cast), x1 = x0+1,
// THEN clip to [0,511]; weights computed from clipped values (matches ref).

#define BH   512
#define BW   512
#define BC   16
#define NB   16

__global__ __launch_bounds__(256) void bilerp_kernel(
    const float* __restrict__ X,
    const float* __restrict__ scale,
    const float* __restrict__ translate,
    float* __restrict__ out)
{
    const int blk = blockIdx.x;      // b * OUT_H + i
    const int b  = blk >> 9;         // / 512
    const int i  = blk & 511;

    const float s  = scale[b];
    const float tx = translate[2 * b];
    const float ty = translate[2 * b + 1];

    // Row-uniform y coordinate and weights
    const float yl = -1.0f + 2.0f * (float)i / 511.0f;
    const float y  = 0.5f * (s * yl + ty + 1.0f) * (float)BH;
    int y0 = (int)y;                 // trunc toward zero, matches astype(int32)
    int y1 = y0 + 1;
    y0 = min(max(y0, 0), BH - 1);
    y1 = min(max(y1, 0), BH - 1);
    const float wy1 = (float)y1 - y;  // (y1f - y)
    const float wy0 = y - (float)y0;  // (y - y0f)

    // Base pointers (float4 granularity; one pixel = 4 float4)
    const float4* __restrict__ Xb   = (const float4*)(X + (size_t)b * BH * BW * BC);
    const float4* __restrict__ row0 = Xb + (size_t)y0 * (BW * (BC / 4));
    const float4* __restrict__ row1 = Xb + (size_t)y1 * (BW * (BC / 4));
    float4* __restrict__ orow = (float4*)(out + (size_t)blk * BW * BC);

    const int tid = threadIdx.x;
    const int q   = tid & 3;         // channel quad within pixel (0..3)
    const int p0  = tid >> 2;        // starting pixel (0..63)

    #pragma unroll
    for (int j = p0; j < BW; j += 64) {
        const float xl = -1.0f + 2.0f * (float)j / 511.0f;
        const float x  = 0.5f * (s * xl + tx + 1.0f) * (float)BW;
        int x0 = (int)x;
        int x1 = x0 + 1;
        x0 = min(max(x0, 0), BW - 1);
        x1 = min(max(x1, 0), BW - 1);
        const float wx1 = (float)x1 - x;
        const float wx0 = x - (float)x0;

        const float wa = wx1 * wy1;
        const float wb = wx1 * wy0;
        const float wc = wx0 * wy1;
        const float wd = wx0 * wy0;

        const float4 pa = row0[x0 * 4 + q];
        const float4 pb = row1[x0 * 4 + q];
        const float4 pc = row0[x1 * 4 + q];
        const float4 pd = row1[x1 * 4 + q];

        float4 o;
        o.x = wa * pa.x + wb * pb.x + wc * pc.x + wd * pd.x;
        o.y = wa * pa.y + wb * pb.y + wc * pc.y + wd * pd.y;
        o.z = wa * pa.z + wb * pb.z + wc * pc.z + wd * pd.z;
        o.w = wa * pa.w + wb * pb.w + wc * pc.w + wd * pd.w;

        orow[j * 4 + q] = o;
    }
}

extern "C" void kernel_launch(void* const* d_in, const int* in_sizes, int n_in,
                              void* d_out, int out_size, void* d_ws, size_t ws_size,
                              hipStream_t stream) {
    const float* X         = (const float*)d_in[0];
    const float* scale     = (const float*)d_in[1];
    const float* translate = (const float*)d_in[2];
    float* out             = (float*)d_out;

    dim3 grid(NB * BH);   // 8192 blocks: one per (batch, output row)
    dim3 block(256);
    bilerp_kernel<<<grid, block, 0, stream>>>(X, scale, translate, out);
}